// Round 4
// baseline (98.034 us; speedup 1.0000x reference)
//
#include <hip/hip_runtime.h>
#include <hip/hip_bf16.h>

#define NPART 8192
#define NCT 4
#define TPB 256
#define NTILE (NPART / TPB)                 // 32
#define NBLK (NTILE * (NTILE + 1) / 2)      // 528 triangular tiles

// ws layout (bytes):
//   0      float acc            (zeroed by prep each call)
//   4      uint  cnt            (zeroed by prep each call)
//   8      int   bf_flag
//   64     float tabs[32]
//   4096   float4 pos4[NPART]   (128 KB, 16B aligned)
//   135168 int   spec[NPART]    (32 KB)

// dtype-generic scalar load: bf16 (upcast) or fp32
__device__ __forceinline__ float loadf(const void* p, int idx, bool bf) {
    if (bf) {
        unsigned int u = ((const unsigned short*)p)[idx];
        return __uint_as_float(u << 16);
    }
    return ((const float*)p)[idx];
}

__global__ __launch_bounds__(TPB) void prep_kernel(const void* __restrict__ eps,
                                                   const void* __restrict__ alp,
                                                   const void* __restrict__ ct,
                                                   const void* __restrict__ rad,
                                                   const void* __restrict__ pos,
                                                   float* __restrict__ acc,
                                                   unsigned int* __restrict__ cnt,
                                                   int* __restrict__ bfflag,
                                                   float* __restrict__ tabs,
                                                   float4* __restrict__ pos4,
                                                   int* __restrict__ spec)
{
    const int t = threadIdx.x;

    // dtype detection: fp32 one-hot words always have low16 == 0
    unsigned int w = ((const unsigned int*)ct)[t & 63];
    const bool bf = (__ballot((w & 0xFFFFu) != 0) != 0ull);

    const int i = blockIdx.x * TPB + t;
    float4 p;
    p.x = loadf(pos, i * 3 + 0, bf);
    p.y = loadf(pos, i * 3 + 1, bf);
    p.z = loadf(pos, i * 3 + 2, bf);
    p.w = loadf(rad, i, bf);
    pos4[i] = p;
    int s = -1;
#pragma unroll
    for (int c = 0; c < NCT; ++c)
        if (loadf(ct, i * NCT + c, bf) > 0.5f) s = c;
    spec[i] = s;

    if (blockIdx.x == 0) {
        if (t == 0) { *acc = 0.0f; *cnt = 0u; *bfflag = bf ? 1 : 0; }
        if (t < 16) {
            int a = t >> 2, c = t & 3;
            float me = (a == c) ? loadf(eps, a * NCT + a, bf)
                                : 0.5f * (loadf(eps, a * NCT + c, bf) + loadf(eps, c * NCT + a, bf));
            float ma = (a == c) ? loadf(alp, a * NCT + a, bf)
                                : 0.5f * (loadf(alp, a * NCT + c, bf) + loadf(alp, c * NCT + a, bf));
            tabs[t]      = 5.0f / (1.0f + __expf(-me)) + 1.0f;   // EPS range
            tabs[16 + t] = 3.0f / (1.0f + __expf(-ma)) + 1.0f;   // ALPHA range
        }
    }
}

__global__ __launch_bounds__(TPB) void pair_kernel(const float4* __restrict__ pos4,
                                                   const int* __restrict__ spec,
                                                   const float* __restrict__ tabs,
                                                   const int* __restrict__ bfflag,
                                                   float* __restrict__ acc_out,
                                                   unsigned int* __restrict__ cnt,
                                                   void* __restrict__ out)
{
    __shared__ float stab[32];
    __shared__ float red[TPB / 64];

    const int t = threadIdx.x;
    if (t < 32) stab[t] = tabs[t];

    // triangular tile decode: linear b -> (bx <= by)
    const int b = blockIdx.x;
    int by = (int)((sqrtf(8.0f * (float)b + 1.0f) - 1.0f) * 0.5f);
    while ((by + 1) * (by + 2) / 2 <= b) ++by;
    while (by * (by + 1) / 2 > b) --by;
    const int bx = b - by * (by + 1) / 2;
    const bool diag = (bx == by);

    const int i = bx * TPB + t;
    const float4 pi = pos4[i];          // per-lane, coalesced
    const int si = spec[i];
    const int j0 = by * TPB;
    const float4* __restrict__ tile = pos4 + j0;   // wave-uniform base

    __syncthreads();

    constexpr float RC2 = 4.0f;            // R_CUTOFF^2
    constexpr float RO2 = 1.7f * 1.7f;     // R_ONSET^2
    constexpr float C1  = RC2 - 3.0f * RO2;
    const float INV_D = 1.0f / ((RC2 - RO2) * (RC2 - RO2) * (RC2 - RO2));

    float acc = 0.0f;
    if (si >= 0) {
#pragma unroll 8
        for (int jj = 0; jj < TPB; ++jj) {
            float4 pj = tile[jj];          // uniform address -> hope for s_load (SMEM)
            float dx = pi.x - pj.x;
            float dy = pi.y - pj.y;
            float dz = pi.z - pj.z;
            float dr2 = fmaf(dx, dx, fmaf(dy, dy, dz * dz));
            if (dr2 < RC2) {               // rare hit (~0.4% of pairs)
                int j = j0 + jj;
                int sj = spec[j];
                if (j != i && sj >= 0) {
                    float e = stab[(si << 2) | sj];
                    float a = stab[16 + ((si << 2) | sj)];
                    float dr = sqrtf(dr2);
                    float ex = __expf(-a * (dr - (pi.w + pj.w)));
                    float om = 1.0f - ex;
                    float u = fmaf(e * om, om, -e);          // eps*(1-ex)^2 - eps
                    float smooth = 1.0f;
                    if (dr2 >= RO2) {
                        float d = RC2 - dr2;
                        smooth = d * d * fmaf(2.0f, dr2, C1) * INV_D;
                    }
                    acc += u * smooth;
                }
            }
        }
    }

    // off-diag tiles cover i<j once; diag tiles need 0.5 * sum_{i!=j}
    acc *= diag ? 0.5f : 1.0f;

    // wave(64) shuffle reduction -> LDS -> block sum
#pragma unroll
    for (int off = 32; off > 0; off >>= 1) acc += __shfl_down(acc, off, 64);
    int lane = t & 63, wv = t >> 6;
    if (lane == 0) red[wv] = acc;
    __syncthreads();

    if (t == 0) {
        float s = red[0] + red[1] + red[2] + red[3];
        atomicAdd(acc_out, s);
        __threadfence();                               // make acc visible device-wide
        unsigned int old = atomicAdd(cnt, 1u);
        if (old == NBLK - 1) {                         // last block: fused finalize
            __threadfence();
            float v = atomicAdd(acc_out, 0.0f);        // coherent device-scope read
            if (*bfflag) ((__hip_bfloat16*)out)[0] = __float2bfloat16(v);
            else         ((float*)out)[0] = v;
        }
    }
}

extern "C" void kernel_launch(void* const* d_in, const int* in_sizes, int n_in,
                              void* d_out, int out_size, void* d_ws, size_t ws_size,
                              hipStream_t stream)
{
    // Map inputs by element count (robust to ordering); eps/alpha both 16 -> keep order.
    const void* eps = nullptr; const void* alp = nullptr;
    const void* ct = nullptr;  const void* rad = nullptr; const void* pos = nullptr;
    int nsmall = 0;
    for (int k = 0; k < n_in; ++k) {
        int s = in_sizes[k];
        if (s == NCT * NCT)        { if (nsmall++ == 0) eps = d_in[k]; else alp = d_in[k]; }
        else if (s == NPART * NCT) ct  = d_in[k];
        else if (s == NPART)       rad = d_in[k];
        else if (s == NPART * 3)   pos = d_in[k];
    }
    if (!eps || !alp || !ct || !rad || !pos) {
        eps = d_in[0]; alp = d_in[1]; ct = d_in[2]; rad = d_in[3]; pos = d_in[4];
    }

    char* ws = (char*)d_ws;
    float*        acc    = (float*)(ws + 0);
    unsigned int* cnt    = (unsigned int*)(ws + 4);
    int*          bfflag = (int*)(ws + 8);
    float*        tabs   = (float*)(ws + 64);
    float4*       pos4   = (float4*)(ws + 4096);
    int*          spec   = (int*)(ws + 4096 + NPART * sizeof(float4));

    prep_kernel<<<NPART / TPB, TPB, 0, stream>>>(eps, alp, ct, rad, pos,
                                                 acc, cnt, bfflag, tabs, pos4, spec);
    pair_kernel<<<NBLK, TPB, 0, stream>>>(pos4, spec, tabs, bfflag, acc, cnt, d_out);
}